// Round 3
// baseline (790.300 us; speedup 1.0000x reference)
//
#include <hip/hip_runtime.h>
#include <hip/hip_bf16.h>

#define B_ 16
#define P_ 1024
#define T_ (B_*P_)

// ---- ws layout (floats). Float inputs/weights staged to f32 up front. ----
constexpr int OFF_FLAG  = 0;      // unused (flag recomputed locally); pad
constexpr int OFF_A     = 16;                       // 95*4 + 4 = 384
constexpr int OFF_TIMES = OFF_A     + 384;          // 16384
constexpr int OFF_VALS  = OFF_TIMES + T_;           // 16384
constexpr int OFF_MASK  = OFF_VALS  + T_;           // 16384
constexpr int OFF_WPSI1 = OFF_MASK  + T_;           // 31*64 = 1984
constexpr int OFF_BPSI1 = OFF_WPSI1 + 1984;         // 64
constexpr int OFF_WPSI2 = OFF_BPSI1 + 64;           // 4096
constexpr int OFF_BPSI2 = OFF_WPSI2 + 4096;         // 64
constexpr int OFF_WKEY  = OFF_BPSI2 + 64;           // 95*128 = 12160
constexpr int OFF_BKEY  = OFF_WKEY  + 12160;        // 128
constexpr int OFF_QRY   = OFF_BKEY  + 128;          // 128
constexpr int OFF_WPHI1 = OFF_QRY   + 128;          // 31*32 = 992
constexpr int OFF_BPHI1 = OFF_WPHI1 + 992;          // 32
constexpr int OFF_WPHI2 = OFF_BPHI1 + 32;           // 1024
constexpr int OFF_BPHI2 = OFF_WPHI2 + 1024;         // 32
constexpr int OFF_WRHO1 = OFF_BPHI2 + 32;           // 128*64 = 8192
constexpr int OFF_BRHO1 = OFF_WRHO1 + 8192;         // 64
constexpr int OFF_WRHO2 = OFF_BRHO1 + 64;           // 4096
constexpr int OFF_BRHO2 = OFF_WRHO2 + 4096;         // 64
constexpr int OFF_PSI   = OFF_BRHO2 + 64;           // T*64
constexpr int OFF_PHI   = OFF_PSI   + T_*64;        // T*32
constexpr int OFF_CUM   = OFF_PHI   + T_*32;        // T*64
constexpr int OFF_PREX  = OFF_CUM   + T_*64;        // T*4
constexpr int OFF_PRE   = OFF_PREX  + T_*4;         // T*4
constexpr int OFF_AGG   = OFF_PRE   + T_*4;         // T*128
// end = OFF_AGG + T_*128 = 4,932,336 floats ~= 18.8 MiB

// dtype detection: non_pad_mask is all 1.0. f32 word0 = 0x3F800000 (low16==0);
// packed bf16 word0 = 0x3F803F80 (low16==0x3F80).
static __device__ __forceinline__ bool detect_f32(const void* mask_raw) {
  const unsigned w = *(const unsigned*)mask_raw;
  return (w & 0xFFFFu) == 0u;
}

static __device__ __forceinline__ float ld_any(const void* src, int i, bool isf32) {
  if (isf32) return ((const float*)src)[i];
  return __bfloat162float(((const __hip_bfloat16*)src)[i]);
}

// ---------- S0: stage all float arrays to f32 in ws ----------
__global__ __launch_bounds__(256) void s0_stage(
    float* __restrict__ ws,
    const void* times, const void* values, const void* mask,
    const void* Wpsi1, const void* bpsi1, const void* Wpsi2, const void* bpsi2,
    const void* Wkey,  const void* bkey,  const void* query,
    const void* Wphi1, const void* bphi1, const void* Wphi2, const void* bphi2,
    const void* Wrho1, const void* brho1, const void* Wrho2, const void* brho2) {
  const bool isf32 = detect_f32(mask);
  const int g  = blockIdx.x * 256 + threadIdx.x;
  const int gs = gridDim.x * 256;
  auto st = [&](int off, const void* src, int n) {
    for (int i = g; i < n; i += gs) ws[off + i] = ld_any(src, i, isf32);
  };
  st(OFF_TIMES, times, T_);   st(OFF_VALS, values, T_);  st(OFF_MASK, mask, T_);
  st(OFF_WPSI1, Wpsi1, 1984); st(OFF_BPSI1, bpsi1, 64);
  st(OFF_WPSI2, Wpsi2, 4096); st(OFF_BPSI2, bpsi2, 64);
  st(OFF_WKEY,  Wkey, 12160); st(OFF_BKEY,  bkey, 128);  st(OFF_QRY, query, 128);
  st(OFF_WPHI1, Wphi1, 992);  st(OFF_BPHI1, bphi1, 32);
  st(OFF_WPHI2, Wphi2, 1024); st(OFF_BPHI2, bphi2, 32);
  st(OFF_WRHO1, Wrho1, 8192); st(OFF_BRHO1, brho1, 64);
  st(OFF_WRHO2, Wrho2, 4096); st(OFF_BRHO2, brho2, 64);
}

// ---------- S1: fold A = (W_key . query)/sqrt(dp), c0 = (b_key . query)/sqrt(dp) ----------
__global__ __launch_bounds__(256) void s1_fold(float* __restrict__ ws) {
  const int gid = blockIdx.x * 256 + threadIdx.x;
  if (gid >= 384) return;
  const float inv_s = 0.17677669529663687f;  // 1/sqrt(32)
  const int h = gid & 3;
  const int j = gid >> 2;  // 0..95; 95 = bias row
  const float* src = (j < 95) ? (ws + OFF_WKEY + j * 128 + h * 32)
                              : (ws + OFF_BKEY + h * 32);
  const float* q = ws + OFF_QRY + h * 32;
  float s = 0.f;
  for (int d = 0; d < 32; ++d) s += src[d] * q[d];
  ws[OFF_A + gid] = s * inv_s;  // A[j][h] at j*4+h; c0[h] at 380+h
}

// ---------- K1: per-token featurize + psi MLP + phi MLP + pre_x ----------
__global__ __launch_bounds__(256) void k1_token(float* __restrict__ ws,
                                                const int* __restrict__ measp) {
  const int t = blockIdx.x * 256 + threadIdx.x;
  if (t >= T_) return;
  const float tval = ws[OFF_TIMES + t];
  const float vval = ws[OFF_VALS + t];
  const float mval = ws[OFF_MASK + t];
  const int   meas = measp[t];

  float x[9];
  const float posv[4] = {1.f, 10.f, 100.f, 1000.f};
  #pragma unroll
  for (int k = 0; k < 4; ++k) {
    const float ang = tval / posv[k];
    x[2*k]   = sinf(ang);
    x[2*k+1] = cosf(ang);
  }
  x[8] = vval;

  const float sel  = (meas > 0) ? 1.f : 0.f;
  const int   mrow = (meas > 0) ? (8 + meas) : 0;  // one-hot row 9..30

  // psi layer 1: 31 -> 64 (9 dense rows + 1 gathered row)
  float h1[64];
  #pragma unroll
  for (int j = 0; j < 64; ++j) h1[j] = ws[OFF_BPSI1 + j];
  #pragma unroll
  for (int i = 0; i < 9; ++i) {
    const float xi = x[i];
    const float* row = ws + OFF_WPSI1 + i * 64;
    #pragma unroll
    for (int j = 0; j < 64; ++j) h1[j] = fmaf(xi, row[j], h1[j]);
  }
  {
    const float* row = ws + OFF_WPSI1 + mrow * 64;
    #pragma unroll
    for (int j = 0; j < 64; ++j) h1[j] = fmaf(sel, row[j], h1[j]);
  }
  #pragma unroll
  for (int j = 0; j < 64; ++j) h1[j] = fmaxf(h1[j], 0.f);

  // psi layer 2: 64 -> 64
  float h2[64];
  #pragma unroll
  for (int j = 0; j < 64; ++j) h2[j] = ws[OFF_BPSI2 + j];
  for (int i = 0; i < 64; ++i) {
    const float a = h1[i];
    const float* row = ws + OFF_WPSI2 + i * 64;
    #pragma unroll
    for (int j = 0; j < 64; ++j) h2[j] = fmaf(a, row[j], h2[j]);
  }
  {
    float* po = ws + OFF_PSI + (size_t)t * 64;
    #pragma unroll
    for (int j = 0; j < 64; ++j) po[j] = fmaxf(h2[j], 0.f) * mval;
  }

  // phi layer 1: 31 -> 32
  float g1[32];
  #pragma unroll
  for (int j = 0; j < 32; ++j) g1[j] = ws[OFF_BPHI1 + j];
  #pragma unroll
  for (int i = 0; i < 9; ++i) {
    const float xi = x[i];
    const float* row = ws + OFF_WPHI1 + i * 32;
    #pragma unroll
    for (int j = 0; j < 32; ++j) g1[j] = fmaf(xi, row[j], g1[j]);
  }
  {
    const float* row = ws + OFF_WPHI1 + mrow * 32;
    #pragma unroll
    for (int j = 0; j < 32; ++j) g1[j] = fmaf(sel, row[j], g1[j]);
  }
  #pragma unroll
  for (int j = 0; j < 32; ++j) g1[j] = fmaxf(g1[j], 0.f);

  // phi layer 2: 32 -> 32
  float g2[32];
  #pragma unroll
  for (int j = 0; j < 32; ++j) g2[j] = ws[OFF_BPHI2 + j];
  for (int i = 0; i < 32; ++i) {
    const float a = g1[i];
    const float* row = ws + OFF_WPHI2 + i * 32;
    #pragma unroll
    for (int j = 0; j < 32; ++j) g2[j] = fmaf(a, row[j], g2[j]);
  }
  {
    float* po = ws + OFF_PHI + (size_t)t * 32;
    #pragma unroll
    for (int j = 0; j < 32; ++j) po[j] = fmaxf(g2[j], 0.f) * mval;
  }

  // pre_x = x . A[0:31,:] + c0
  float pr[4];
  #pragma unroll
  for (int h = 0; h < 4; ++h) pr[h] = ws[OFF_A + 380 + h];
  #pragma unroll
  for (int i = 0; i < 9; ++i) {
    const float xi = x[i];
    #pragma unroll
    for (int h = 0; h < 4; ++h) pr[h] = fmaf(xi, ws[OFF_A + i * 4 + h], pr[h]);
  }
  #pragma unroll
  for (int h = 0; h < 4; ++h) pr[h] = fmaf(sel, ws[OFF_A + mrow * 4 + h], pr[h]);
  #pragma unroll
  for (int h = 0; h < 4; ++h) ws[OFF_PREX + (size_t)t * 4 + h] = pr[h];
}

// ---------- K2: cumulative mean of psi along p, per (batch, channel) ----------
__global__ __launch_bounds__(64) void k2_cum(float* __restrict__ ws) {
  const int b = blockIdx.x;
  const int c = threadIdx.x;  // 0..63
  const float* psiB = ws + OFF_PSI + (size_t)b * P_ * 64;
  float*       cumB = ws + OFF_CUM + (size_t)b * P_ * 64;
  const float* mB   = ws + OFF_MASK + b * P_;
  float S = 0.f, cnt = 0.f;
  for (int p = 0; p < P_; ++p) {
    cnt += mB[p];
    S   += psiB[p * 64 + c];
    cumB[p * 64 + c] = S / cnt;
  }
}

// ---------- K3: pre = pre_x + cum . A[31:95,:] ----------
__global__ __launch_bounds__(256) void k3_pre(float* __restrict__ ws) {
  const int t = blockIdx.x * 256 + threadIdx.x;
  if (t >= T_) return;
  const float* cumt = ws + OFF_CUM + (size_t)t * 64;
  float a[4];
  #pragma unroll
  for (int h = 0; h < 4; ++h) a[h] = ws[OFF_PREX + (size_t)t * 4 + h];
  for (int c = 0; c < 64; ++c) {
    const float cv = cumt[c];
    #pragma unroll
    for (int h = 0; h < 4; ++h) a[h] = fmaf(cv, ws[OFF_A + (31 + c) * 4 + h], a[h]);
  }
  #pragma unroll
  for (int h = 0; h < 4; ++h) ws[OFF_PRE + (size_t)t * 4 + h] = a[h];
}

// ---------- K4: online-softmax cumulative aggregation ----------
// block = 128: h = tid>>5 (4 heads), d = tid&31 (32 dims); one block per batch
__global__ __launch_bounds__(128) void k4_scan(float* __restrict__ ws) {
  const int b = blockIdx.x;
  const int h = threadIdx.x >> 5;
  const int d = threadIdx.x & 31;
  const float* preB = ws + OFF_PRE + (size_t)b * P_ * 4;
  const float* phiB = ws + OFF_PHI + (size_t)b * P_ * 32;
  float*       aggB = ws + OFF_AGG + (size_t)b * P_ * 128;
  const float* mB   = ws + OFF_MASK + b * P_;

  float M = -__builtin_inff();
  float E = 0.f, S = 0.f;
  for (int p = 0; p < P_; ++p) {
    const float v  = preB[p * 4 + h];
    const float ph = phiB[p * 32 + d];
    const float mv = mB[p];
    const float nM = fmaxf(M, v);
    const float al = __expf(M - nM);
    const float w  = __expf(v - nM);
    E = fmaf(E, al, w);
    S = fmaf(S, al, w * ph);
    M = nM;
    aggB[p * 128 + h * 32 + d] = (S / E) * mv;
  }
}

// ---------- K5: rho MLP 128 -> 64 -> 64; dtype-adaptive output store ----------
__global__ __launch_bounds__(256) void k5_rho(const float* __restrict__ ws,
                                              const void* __restrict__ mask_raw,
                                              void* __restrict__ out) {
  const int t = blockIdx.x * 256 + threadIdx.x;
  if (t >= T_) return;
  const bool isf32 = detect_f32(mask_raw);
  const float mval = ws[OFF_MASK + t];
  const float* aggt = ws + OFF_AGG + (size_t)t * 128;

  float h1[64];
  #pragma unroll
  for (int j = 0; j < 64; ++j) h1[j] = ws[OFF_BRHO1 + j];
  for (int i = 0; i < 128; ++i) {
    const float a = aggt[i];
    const float* row = ws + OFF_WRHO1 + i * 64;
    #pragma unroll
    for (int j = 0; j < 64; ++j) h1[j] = fmaf(a, row[j], h1[j]);
  }
  #pragma unroll
  for (int j = 0; j < 64; ++j) h1[j] = fmaxf(h1[j], 0.f);

  float h2[64];
  #pragma unroll
  for (int j = 0; j < 64; ++j) h2[j] = ws[OFF_BRHO2 + j];
  for (int i = 0; i < 64; ++i) {
    const float a = h1[i];
    const float* row = ws + OFF_WRHO2 + i * 64;
    #pragma unroll
    for (int j = 0; j < 64; ++j) h2[j] = fmaf(a, row[j], h2[j]);
  }

  if (isf32) {
    float* po = (float*)out + (size_t)t * 64;
    #pragma unroll
    for (int j = 0; j < 64; ++j) po[j] = fmaxf(h2[j], 0.f) * mval;
  } else {
    unsigned* po = (unsigned*)((__hip_bfloat16*)out + (size_t)t * 64);
    #pragma unroll
    for (int k = 0; k < 32; ++k) {
      const float r0 = fmaxf(h2[2*k],   0.f) * mval;
      const float r1 = fmaxf(h2[2*k+1], 0.f) * mval;
      __hip_bfloat16 b0 = __float2bfloat16(r0), b1 = __float2bfloat16(r1);
      unsigned short u0, u1;
      __builtin_memcpy(&u0, &b0, 2); __builtin_memcpy(&u1, &b1, 2);
      po[k] = (unsigned)u0 | ((unsigned)u1 << 16);
    }
  }
}

extern "C" void kernel_launch(void* const* d_in, const int* in_sizes, int n_in,
                              void* d_out, int out_size, void* d_ws, size_t ws_size,
                              hipStream_t stream) {
  const void* times  = d_in[0];
  const void* values = d_in[1];
  const int*  meas   = (const int*)d_in[2];
  const void* mask   = d_in[3];
  const void* Wpsi1  = d_in[4];
  const void* bpsi1  = d_in[5];
  const void* Wpsi2  = d_in[6];
  const void* bpsi2  = d_in[7];
  const void* Wkey   = d_in[8];
  const void* bkey   = d_in[9];
  const void* query  = d_in[10];
  const void* Wphi1  = d_in[11];
  const void* bphi1  = d_in[12];
  const void* Wphi2  = d_in[13];
  const void* bphi2  = d_in[14];
  const void* Wrho1  = d_in[15];
  const void* brho1  = d_in[16];
  const void* Wrho2  = d_in[17];
  const void* brho2  = d_in[18];
  float* ws = (float*)d_ws;

  s0_stage<<<96, 256, 0, stream>>>(ws, times, values, mask,
                                   Wpsi1, bpsi1, Wpsi2, bpsi2,
                                   Wkey, bkey, query,
                                   Wphi1, bphi1, Wphi2, bphi2,
                                   Wrho1, brho1, Wrho2, brho2);
  s1_fold<<<2, 256, 0, stream>>>(ws);
  k1_token<<<T_/256, 256, 0, stream>>>(ws, meas);
  k2_cum<<<B_, 64, 0, stream>>>(ws);
  k3_pre<<<T_/256, 256, 0, stream>>>(ws);
  k4_scan<<<B_, 128, 0, stream>>>(ws);
  k5_rho<<<T_/256, 256, 0, stream>>>(ws, mask, d_out);
}

// Round 4
// 243.303 us; speedup vs baseline: 3.2482x; 3.2482x over previous
//
#include <hip/hip_runtime.h>
#include <hip/hip_bf16.h>

#define B_ 16
#define P_ 1024
#define T_ (B_*P_)
#define CH_ 16          // chunks per batch for the softmax scan
#define CL_ (P_/CH_)    // 64 positions per chunk

// ---- ws layout (floats). Float inputs/weights staged to f32 up front. ----
constexpr int OFF_A     = 16;                       // 95*4 + 4 = 384
constexpr int OFF_TIMES = OFF_A     + 384;
constexpr int OFF_VALS  = OFF_TIMES + T_;
constexpr int OFF_MASK  = OFF_VALS  + T_;
constexpr int OFF_WPSI1 = OFF_MASK  + T_;           // 31*64 = 1984
constexpr int OFF_BPSI1 = OFF_WPSI1 + 1984;         // 64
constexpr int OFF_WPSI2 = OFF_BPSI1 + 64;           // 4096
constexpr int OFF_BPSI2 = OFF_WPSI2 + 4096;         // 64
constexpr int OFF_WKEY  = OFF_BPSI2 + 64;           // 12160
constexpr int OFF_BKEY  = OFF_WKEY  + 12160;        // 128
constexpr int OFF_QRY   = OFF_BKEY  + 128;          // 128
constexpr int OFF_WPHI1 = OFF_QRY   + 128;          // 992
constexpr int OFF_BPHI1 = OFF_WPHI1 + 992;          // 32
constexpr int OFF_WPHI2 = OFF_BPHI1 + 32;           // 1024
constexpr int OFF_BPHI2 = OFF_WPHI2 + 1024;         // 32
constexpr int OFF_WRHO1 = OFF_BPHI2 + 32;           // 8192
constexpr int OFF_BRHO1 = OFF_WRHO1 + 8192;         // 64
constexpr int OFF_WRHO2 = OFF_BRHO1 + 64;           // 4096
constexpr int OFF_BRHO2 = OFF_WRHO2 + 4096;         // 64
constexpr int OFF_PHI   = OFF_BRHO2 + 64;           // T*32
constexpr int OFF_Z     = OFF_PHI   + T_*32;        // T*4   z = (psi*m).A2
constexpr int OFF_PREX  = OFF_Z     + T_*4;         // T*4
constexpr int OFF_PRE   = OFF_PREX  + T_*4;         // T*4
constexpr int OFF_AGG   = OFF_PRE   + T_*4;         // T*128
constexpr int OFF_CME   = OFF_AGG   + T_*128;       // B*CH*4*2 = 2048 chunk (M,E)
constexpr int OFF_CS    = OFF_CME   + 2048;         // B*CH*128 = 32768 chunk S
constexpr int OFF_PME   = OFF_CS    + 32768;        // 2048 prefix (M,E)
constexpr int OFF_PS    = OFF_PME   + 2048;         // 32768 prefix S
// end ~= 11.1 MiB

// dtype detection: non_pad_mask is all 1.0. f32 word0 low16 == 0; bf16-pair != 0.
static __device__ __forceinline__ bool detect_f32(const void* mask_raw) {
  return ((*(const unsigned*)mask_raw) & 0xFFFFu) == 0u;
}
static __device__ __forceinline__ float ld_any(const void* src, int i, bool isf32) {
  if (isf32) return ((const float*)src)[i];
  return __bfloat162float(((const __hip_bfloat16*)src)[i]);
}

// ---------- S0: stage all float arrays to f32 in ws ----------
__global__ __launch_bounds__(256) void s0_stage(
    float* __restrict__ ws,
    const void* times, const void* values, const void* mask,
    const void* Wpsi1, const void* bpsi1, const void* Wpsi2, const void* bpsi2,
    const void* Wkey,  const void* bkey,  const void* query,
    const void* Wphi1, const void* bphi1, const void* Wphi2, const void* bphi2,
    const void* Wrho1, const void* brho1, const void* Wrho2, const void* brho2) {
  const bool isf32 = detect_f32(mask);
  const int g  = blockIdx.x * 256 + threadIdx.x;
  const int gs = gridDim.x * 256;
  auto st = [&](int off, const void* src, int n) {
    for (int i = g; i < n; i += gs) ws[off + i] = ld_any(src, i, isf32);
  };
  st(OFF_TIMES, times, T_);   st(OFF_VALS, values, T_);  st(OFF_MASK, mask, T_);
  st(OFF_WPSI1, Wpsi1, 1984); st(OFF_BPSI1, bpsi1, 64);
  st(OFF_WPSI2, Wpsi2, 4096); st(OFF_BPSI2, bpsi2, 64);
  st(OFF_WKEY,  Wkey, 12160); st(OFF_BKEY,  bkey, 128);  st(OFF_QRY, query, 128);
  st(OFF_WPHI1, Wphi1, 992);  st(OFF_BPHI1, bphi1, 32);
  st(OFF_WPHI2, Wphi2, 1024); st(OFF_BPHI2, bphi2, 32);
  st(OFF_WRHO1, Wrho1, 8192); st(OFF_BRHO1, brho1, 64);
  st(OFF_WRHO2, Wrho2, 4096); st(OFF_BRHO2, brho2, 64);
}

// ---------- S1: fold A = (W_key . query)/sqrt(dp) ----------
__global__ __launch_bounds__(256) void s1_fold(float* __restrict__ ws) {
  const int gid = blockIdx.x * 256 + threadIdx.x;
  if (gid >= 384) return;
  const float inv_s = 0.17677669529663687f;
  const int h = gid & 3;
  const int j = gid >> 2;  // 0..95; 95 = bias row
  const float* src = (j < 95) ? (ws + OFF_WKEY + j * 128 + h * 32)
                              : (ws + OFF_BKEY + h * 32);
  const float* q = ws + OFF_QRY + h * 32;
  float s = 0.f;
  for (int d = 0; d < 32; ++d) s += src[d] * q[d];
  ws[OFF_A + gid] = s * inv_s;  // A[j][h] at j*4+h; c0[h] at 380+h
}

// ---------- K1: featurize + psi MLP + z=(psi*m).A2 + phi MLP + pre_x ----------
__global__ __launch_bounds__(256) void k1_token(float* __restrict__ ws,
                                                const int* __restrict__ measp) {
  const int t = blockIdx.x * 256 + threadIdx.x;
  if (t >= T_) return;
  const float tval = ws[OFF_TIMES + t];
  const float vval = ws[OFF_VALS + t];
  const float mval = ws[OFF_MASK + t];
  const int   meas = measp[t];

  float x[9];
  const float posv[4] = {1.f, 10.f, 100.f, 1000.f};
  #pragma unroll
  for (int k = 0; k < 4; ++k) {
    const float ang = tval / posv[k];
    x[2*k]   = sinf(ang);
    x[2*k+1] = cosf(ang);
  }
  x[8] = vval;

  const float sel  = (meas > 0) ? 1.f : 0.f;
  const int   mrow = (meas > 0) ? (8 + meas) : 0;

  // psi layer 1: 31 -> 64
  float h1[64];
  #pragma unroll
  for (int j = 0; j < 64; ++j) h1[j] = ws[OFF_BPSI1 + j];
  #pragma unroll
  for (int i = 0; i < 9; ++i) {
    const float xi = x[i];
    const float* row = ws + OFF_WPSI1 + i * 64;
    #pragma unroll
    for (int j = 0; j < 64; ++j) h1[j] = fmaf(xi, row[j], h1[j]);
  }
  {
    const float* row = ws + OFF_WPSI1 + mrow * 64;
    #pragma unroll
    for (int j = 0; j < 64; ++j) h1[j] = fmaf(sel, row[j], h1[j]);
  }
  #pragma unroll
  for (int j = 0; j < 64; ++j) h1[j] = fmaxf(h1[j], 0.f);

  // psi layer 2: 64 -> 64
  float h2[64];
  #pragma unroll
  for (int j = 0; j < 64; ++j) h2[j] = ws[OFF_BPSI2 + j];
  for (int i = 0; i < 64; ++i) {
    const float a = h1[i];
    const float* row = ws + OFF_WPSI2 + i * 64;
    #pragma unroll
    for (int j = 0; j < 64; ++j) h2[j] = fmaf(a, row[j], h2[j]);
  }

  // z[h] = sum_c relu(h2[c])*m * A2[c][h]   (A2 row c at OFF_A + (31+c)*4)
  {
    float z0 = 0.f, z1 = 0.f, z2 = 0.f, z3 = 0.f;
    for (int c = 0; c < 64; ++c) {
      const float q = fmaxf(h2[c], 0.f) * mval;
      const float* a2 = ws + OFF_A + (31 + c) * 4;
      z0 = fmaf(q, a2[0], z0); z1 = fmaf(q, a2[1], z1);
      z2 = fmaf(q, a2[2], z2); z3 = fmaf(q, a2[3], z3);
    }
    float* zo = ws + OFF_Z + (size_t)t * 4;
    zo[0] = z0; zo[1] = z1; zo[2] = z2; zo[3] = z3;
  }

  // phi layer 1: 31 -> 32
  float g1[32];
  #pragma unroll
  for (int j = 0; j < 32; ++j) g1[j] = ws[OFF_BPHI1 + j];
  #pragma unroll
  for (int i = 0; i < 9; ++i) {
    const float xi = x[i];
    const float* row = ws + OFF_WPHI1 + i * 32;
    #pragma unroll
    for (int j = 0; j < 32; ++j) g1[j] = fmaf(xi, row[j], g1[j]);
  }
  {
    const float* row = ws + OFF_WPHI1 + mrow * 32;
    #pragma unroll
    for (int j = 0; j < 32; ++j) g1[j] = fmaf(sel, row[j], g1[j]);
  }
  #pragma unroll
  for (int j = 0; j < 32; ++j) g1[j] = fmaxf(g1[j], 0.f);

  // phi layer 2: 32 -> 32
  float g2[32];
  #pragma unroll
  for (int j = 0; j < 32; ++j) g2[j] = ws[OFF_BPHI2 + j];
  for (int i = 0; i < 32; ++i) {
    const float a = g1[i];
    const float* row = ws + OFF_WPHI2 + i * 32;
    #pragma unroll
    for (int j = 0; j < 32; ++j) g2[j] = fmaf(a, row[j], g2[j]);
  }
  {
    float* po = ws + OFF_PHI + (size_t)t * 32;
    #pragma unroll
    for (int j = 0; j < 32; ++j) po[j] = fmaxf(g2[j], 0.f) * mval;
  }

  // pre_x = x . A[0:31,:] + c0
  float pr[4];
  #pragma unroll
  for (int h = 0; h < 4; ++h) pr[h] = ws[OFF_A + 380 + h];
  #pragma unroll
  for (int i = 0; i < 9; ++i) {
    const float xi = x[i];
    #pragma unroll
    for (int h = 0; h < 4; ++h) pr[h] = fmaf(xi, ws[OFF_A + i * 4 + h], pr[h]);
  }
  #pragma unroll
  for (int h = 0; h < 4; ++h) pr[h] = fmaf(sel, ws[OFF_A + mrow * 4 + h], pr[h]);
  #pragma unroll
  for (int h = 0; h < 4; ++h) ws[OFF_PREX + (size_t)t * 4 + h] = pr[h];
}

// ---------- K2': block-parallel scan of (cnt, z[4]) -> pre ----------
// one block per batch; 256 threads x 4 consecutive positions each
__global__ __launch_bounds__(256) void k2_scanz(float* __restrict__ ws) {
  const int b   = blockIdx.x;
  const int tid = threadIdx.x;
  __shared__ float sc[256], s0[256], s1[256], s2[256], s3[256];

  const float* mB = ws + OFF_MASK + b * P_;
  const float* zB = ws + OFF_Z    + (size_t)b * P_ * 4;
  const int p0 = tid * 4;

  float lc[4], l0[4], l1[4], l2[4], l3[4];
  float c = 0.f, z0 = 0.f, z1 = 0.f, z2 = 0.f, z3 = 0.f;
  #pragma unroll
  for (int i = 0; i < 4; ++i) {
    c  += mB[p0 + i];
    z0 += zB[(p0 + i) * 4 + 0]; z1 += zB[(p0 + i) * 4 + 1];
    z2 += zB[(p0 + i) * 4 + 2]; z3 += zB[(p0 + i) * 4 + 3];
    lc[i] = c; l0[i] = z0; l1[i] = z1; l2[i] = z2; l3[i] = z3;
  }

  float rc = c, r0 = z0, r1 = z1, r2 = z2, r3 = z3;
  sc[tid] = rc; s0[tid] = r0; s1[tid] = r1; s2[tid] = r2; s3[tid] = r3;
  __syncthreads();
  for (int off = 1; off < 256; off <<= 1) {
    float ac = 0.f, a0 = 0.f, a1 = 0.f, a2 = 0.f, a3 = 0.f;
    if (tid >= off) {
      ac = sc[tid - off]; a0 = s0[tid - off]; a1 = s1[tid - off];
      a2 = s2[tid - off]; a3 = s3[tid - off];
    }
    __syncthreads();
    rc += ac; r0 += a0; r1 += a1; r2 += a2; r3 += a3;
    sc[tid] = rc; s0[tid] = r0; s1[tid] = r1; s2[tid] = r2; s3[tid] = r3;
    __syncthreads();
  }
  // exclusive prefix for this thread
  const float ec = rc - c, e0 = r0 - z0, e1 = r1 - z1, e2 = r2 - z2, e3 = r3 - z3;

  const float* px  = ws + OFF_PREX + (size_t)b * P_ * 4;
  float*       pre = ws + OFF_PRE  + (size_t)b * P_ * 4;
  #pragma unroll
  for (int i = 0; i < 4; ++i) {
    const float inv = 1.f / (ec + lc[i]);
    const int p = p0 + i;
    pre[p * 4 + 0] = px[p * 4 + 0] + (e0 + l0[i]) * inv;
    pre[p * 4 + 1] = px[p * 4 + 1] + (e1 + l1[i]) * inv;
    pre[p * 4 + 2] = px[p * 4 + 2] + (e2 + l2[i]) * inv;
    pre[p * 4 + 3] = px[p * 4 + 3] + (e3 + l3[i]) * inv;
  }
}

// ---------- K4a: per-chunk softmax-state reduction ----------
// grid (CH_, B_), block 128: h = tid>>5, d = tid&31
__global__ __launch_bounds__(128) void k4a_chunk(float* __restrict__ ws) {
  const int ch = blockIdx.x, b = blockIdx.y;
  const int h = threadIdx.x >> 5, d = threadIdx.x & 31;
  const float* preB = ws + OFF_PRE + (size_t)b * P_ * 4;
  const float* phiB = ws + OFF_PHI + (size_t)b * P_ * 32;

  float M = -__builtin_inff(), E = 0.f, S = 0.f;
  const int pbeg = ch * CL_;
  for (int p = pbeg; p < pbeg + CL_; ++p) {
    const float v  = preB[p * 4 + h];
    const float ph = phiB[p * 32 + d];
    const float nM = fmaxf(M, v);
    const float al = __expf(M - nM);
    const float w  = __expf(v - nM);
    E = fmaf(E, al, w);
    S = fmaf(S, al, w * ph);
    M = nM;
  }
  const int base = (b * CH_ + ch) * 4 + h;
  if (d == 0) { ws[OFF_CME + base * 2] = M; ws[OFF_CME + base * 2 + 1] = E; }
  ws[OFF_CS + base * 32 + d] = S;
}

// ---------- K4b: exclusive scan of chunk states ----------
// grid B_, block 128
__global__ __launch_bounds__(128) void k4b_prefix(float* __restrict__ ws) {
  const int b = blockIdx.x;
  const int h = threadIdx.x >> 5, d = threadIdx.x & 31;
  float M = -__builtin_inff(), E = 0.f, S = 0.f;
  for (int ch = 0; ch < CH_; ++ch) {
    const int base = (b * CH_ + ch) * 4 + h;
    if (d == 0) { ws[OFF_PME + base * 2] = M; ws[OFF_PME + base * 2 + 1] = E; }
    ws[OFF_PS + base * 32 + d] = S;
    const float cM = ws[OFF_CME + base * 2];
    const float cE = ws[OFF_CME + base * 2 + 1];
    const float cS = ws[OFF_CS  + base * 32 + d];
    const float nM = fmaxf(M, cM);
    const float a1 = __expf(M - nM);
    const float a2 = __expf(cM - nM);
    E = E * a1 + cE * a2;
    S = S * a1 + cS * a2;
    M = nM;
  }
}

// ---------- K4c: replay chunk from prefix, write agg ----------
// grid (CH_, B_), block 128
__global__ __launch_bounds__(128) void k4c_replay(float* __restrict__ ws) {
  const int ch = blockIdx.x, b = blockIdx.y;
  const int h = threadIdx.x >> 5, d = threadIdx.x & 31;
  const float* preB = ws + OFF_PRE + (size_t)b * P_ * 4;
  const float* phiB = ws + OFF_PHI + (size_t)b * P_ * 32;
  const float* mB   = ws + OFF_MASK + b * P_;
  float*       aggB = ws + OFF_AGG + (size_t)b * P_ * 128;

  const int base = (b * CH_ + ch) * 4 + h;
  float M = ws[OFF_PME + base * 2];
  float E = ws[OFF_PME + base * 2 + 1];
  float S = ws[OFF_PS  + base * 32 + d];

  const int pbeg = ch * CL_;
  for (int p = pbeg; p < pbeg + CL_; ++p) {
    const float v  = preB[p * 4 + h];
    const float ph = phiB[p * 32 + d];
    const float nM = fmaxf(M, v);
    const float al = __expf(M - nM);
    const float w  = __expf(v - nM);
    E = fmaf(E, al, w);
    S = fmaf(S, al, w * ph);
    M = nM;
    aggB[p * 128 + h * 32 + d] = (S / E) * mB[p];
  }
}

// ---------- K5: rho MLP 128 -> 64 -> 64; dtype-adaptive output ----------
__global__ __launch_bounds__(256) void k5_rho(const float* __restrict__ ws,
                                              const void* __restrict__ mask_raw,
                                              void* __restrict__ out) {
  const int t = blockIdx.x * 256 + threadIdx.x;
  if (t >= T_) return;
  const bool isf32 = detect_f32(mask_raw);
  const float mval = ws[OFF_MASK + t];
  const float* aggt = ws + OFF_AGG + (size_t)t * 128;

  float h1[64];
  #pragma unroll
  for (int j = 0; j < 64; ++j) h1[j] = ws[OFF_BRHO1 + j];
  for (int i = 0; i < 128; ++i) {
    const float a = aggt[i];
    const float* row = ws + OFF_WRHO1 + i * 64;
    #pragma unroll
    for (int j = 0; j < 64; ++j) h1[j] = fmaf(a, row[j], h1[j]);
  }
  #pragma unroll
  for (int j = 0; j < 64; ++j) h1[j] = fmaxf(h1[j], 0.f);

  float h2[64];
  #pragma unroll
  for (int j = 0; j < 64; ++j) h2[j] = ws[OFF_BRHO2 + j];
  for (int i = 0; i < 64; ++i) {
    const float a = h1[i];
    const float* row = ws + OFF_WRHO2 + i * 64;
    #pragma unroll
    for (int j = 0; j < 64; ++j) h2[j] = fmaf(a, row[j], h2[j]);
  }

  if (isf32) {
    float* po = (float*)out + (size_t)t * 64;
    #pragma unroll
    for (int j = 0; j < 64; ++j) po[j] = fmaxf(h2[j], 0.f) * mval;
  } else {
    unsigned* po = (unsigned*)((__hip_bfloat16*)out + (size_t)t * 64);
    #pragma unroll
    for (int k = 0; k < 32; ++k) {
      const float r0 = fmaxf(h2[2*k],   0.f) * mval;
      const float r1 = fmaxf(h2[2*k+1], 0.f) * mval;
      __hip_bfloat16 b0 = __float2bfloat16(r0), b1 = __float2bfloat16(r1);
      unsigned short u0, u1;
      __builtin_memcpy(&u0, &b0, 2); __builtin_memcpy(&u1, &b1, 2);
      po[k] = (unsigned)u0 | ((unsigned)u1 << 16);
    }
  }
}

extern "C" void kernel_launch(void* const* d_in, const int* in_sizes, int n_in,
                              void* d_out, int out_size, void* d_ws, size_t ws_size,
                              hipStream_t stream) {
  const void* times  = d_in[0];
  const void* values = d_in[1];
  const int*  meas   = (const int*)d_in[2];
  const void* mask   = d_in[3];
  float* ws = (float*)d_ws;

  s0_stage<<<96, 256, 0, stream>>>(ws, times, values, mask,
                                   d_in[4], d_in[5], d_in[6], d_in[7],
                                   d_in[8], d_in[9], d_in[10],
                                   d_in[11], d_in[12], d_in[13], d_in[14],
                                   d_in[15], d_in[16], d_in[17], d_in[18]);
  s1_fold<<<2, 256, 0, stream>>>(ws);
  k1_token<<<T_/256, 256, 0, stream>>>(ws, meas);
  k2_scanz<<<B_, 256, 0, stream>>>(ws);
  k4a_chunk<<<dim3(CH_, B_), 128, 0, stream>>>(ws);
  k4b_prefix<<<B_, 128, 0, stream>>>(ws);
  k4c_replay<<<dim3(CH_, B_), 128, 0, stream>>>(ws);
  k5_rho<<<T_/256, 256, 0, stream>>>(ws, mask, d_out);
}

// Round 5
// 170.828 us; speedup vs baseline: 4.6263x; 1.4243x over previous
//
#include <hip/hip_runtime.h>
#include <hip/hip_bf16.h>

#define B_ 16
#define P_ 1024
#define T_ (B_*P_)
#define CH_ 16          // chunks per batch for the softmax scan
#define CL_ (P_/CH_)    // 64 positions per chunk

// ---- ws layout (floats). Float inputs/weights staged to f32 up front. ----
constexpr int OFF_A     = 16;                       // 95*4 + 4 = 384
constexpr int OFF_TIMES = OFF_A     + 384;
constexpr int OFF_VALS  = OFF_TIMES + T_;
constexpr int OFF_MASK  = OFF_VALS  + T_;
constexpr int OFF_WPSI1 = OFF_MASK  + T_;           // 1984
constexpr int OFF_BPSI1 = OFF_WPSI1 + 1984;         // 64
constexpr int OFF_WPSI2 = OFF_BPSI1 + 64;           // 4096
constexpr int OFF_BPSI2 = OFF_WPSI2 + 4096;         // 64
constexpr int OFF_WKEY  = OFF_BPSI2 + 64;           // 12160
constexpr int OFF_BKEY  = OFF_WKEY  + 12160;        // 128
constexpr int OFF_QRY   = OFF_BKEY  + 128;          // 128
constexpr int OFF_WPHI1 = OFF_QRY   + 128;          // 992
constexpr int OFF_BPHI1 = OFF_WPHI1 + 992;          // 32
constexpr int OFF_WPHI2 = OFF_BPHI1 + 32;           // 1024
constexpr int OFF_BPHI2 = OFF_WPHI2 + 1024;         // 32
constexpr int OFF_WRHO1 = OFF_BPHI2 + 32;           // 8192
constexpr int OFF_BRHO1 = OFF_WRHO1 + 8192;         // 64
constexpr int OFF_WRHO2 = OFF_BRHO1 + 64;           // 4096
constexpr int OFF_BRHO2 = OFF_WRHO2 + 4096;         // 64
constexpr int OFF_PHI   = OFF_BRHO2 + 64;           // T*32
constexpr int OFF_Z     = OFF_PHI   + T_*32;        // T*4
constexpr int OFF_PREX  = OFF_Z     + T_*4;         // T*4
constexpr int OFF_PRE   = OFF_PREX  + T_*4;         // T*4
constexpr int OFF_AGG   = OFF_PRE   + T_*4;         // T*128
constexpr int OFF_CME   = OFF_AGG   + T_*128;       // 2048
constexpr int OFF_CS    = OFF_CME   + 2048;         // 32768
constexpr int OFF_PME   = OFF_CS    + 32768;        // 2048
constexpr int OFF_PS    = OFF_PME   + 2048;         // 32768

static __device__ __forceinline__ bool detect_f32(const void* mask_raw) {
  return ((*(const unsigned*)mask_raw) & 0xFFFFu) == 0u;
}
static __device__ __forceinline__ float ld_any(const void* src, int i, bool isf32) {
  if (isf32) return ((const float*)src)[i];
  return __bfloat162float(((const __hip_bfloat16*)src)[i]);
}

// ---------- S0: stage all float arrays to f32 in ws ----------
__global__ __launch_bounds__(256) void s0_stage(
    float* __restrict__ ws,
    const void* times, const void* values, const void* mask,
    const void* Wpsi1, const void* bpsi1, const void* Wpsi2, const void* bpsi2,
    const void* Wkey,  const void* bkey,  const void* query,
    const void* Wphi1, const void* bphi1, const void* Wphi2, const void* bphi2,
    const void* Wrho1, const void* brho1, const void* Wrho2, const void* brho2) {
  const bool isf32 = detect_f32(mask);
  const int g  = blockIdx.x * 256 + threadIdx.x;
  const int gs = gridDim.x * 256;
  auto st = [&](int off, const void* src, int n) {
    for (int i = g; i < n; i += gs) ws[off + i] = ld_any(src, i, isf32);
  };
  st(OFF_TIMES, times, T_);   st(OFF_VALS, values, T_);  st(OFF_MASK, mask, T_);
  st(OFF_WPSI1, Wpsi1, 1984); st(OFF_BPSI1, bpsi1, 64);
  st(OFF_WPSI2, Wpsi2, 4096); st(OFF_BPSI2, bpsi2, 64);
  st(OFF_WKEY,  Wkey, 12160); st(OFF_BKEY,  bkey, 128);  st(OFF_QRY, query, 128);
  st(OFF_WPHI1, Wphi1, 992);  st(OFF_BPHI1, bphi1, 32);
  st(OFF_WPHI2, Wphi2, 1024); st(OFF_BPHI2, bphi2, 32);
  st(OFF_WRHO1, Wrho1, 8192); st(OFF_BRHO1, brho1, 64);
  st(OFF_WRHO2, Wrho2, 4096); st(OFF_BRHO2, brho2, 64);
}

// ---------- S1: fold A = (W_key . query)/sqrt(dp) ----------
__global__ __launch_bounds__(256) void s1_fold(float* __restrict__ ws) {
  const int gid = blockIdx.x * 256 + threadIdx.x;
  if (gid >= 384) return;
  const float inv_s = 0.17677669529663687f;
  const int h = gid & 3;
  const int j = gid >> 2;
  const float* src = (j < 95) ? (ws + OFF_WKEY + j * 128 + h * 32)
                              : (ws + OFF_BKEY + h * 32);
  const float* q = ws + OFF_QRY + h * 32;
  float s = 0.f;
  for (int d = 0; d < 32; ++d) s += src[d] * q[d];
  ws[OFF_A + gid] = s * inv_s;  // A[j][h] at j*4+h; c0[h] at 380+h
}

// ---------- K1: wave-per-token MLPs. 4 tokens/block, lane=channel ----------
__global__ __launch_bounds__(256) void k1_token(float* __restrict__ ws,
                                                const int* __restrict__ measp) {
  __shared__ float sh1[4][64];
  __shared__ float sg1[4][32];
  const int tid = threadIdx.x;
  const int wv  = __builtin_amdgcn_readfirstlane(tid >> 6);
  const int j   = tid & 63;
  const int t   = blockIdx.x * 4 + wv;

  const float tval = ws[OFF_TIMES + t];  // wave-uniform -> s_load
  const float vval = ws[OFF_VALS + t];
  const float mval = ws[OFF_MASK + t];
  const int   meas = measp[t];
  const float sel  = (meas > 0) ? 1.f : 0.f;
  const int   mrow = (meas > 0) ? (8 + meas) : 0;

  float x[9];
  const float posv[4] = {1.f, 10.f, 100.f, 1000.f};
  #pragma unroll
  for (int k = 0; k < 4; ++k) {
    float s, c;
    __sincosf(tval / posv[k], &s, &c);
    x[2*k] = s; x[2*k+1] = c;
  }
  x[8] = vval;

  // psi L1, channel j (weight rows L1-hot, coalesced)
  float h1 = ws[OFF_BPSI1 + j];
  #pragma unroll
  for (int i = 0; i < 9; ++i) h1 = fmaf(x[i], ws[OFF_WPSI1 + i * 64 + j], h1);
  h1 = fmaf(sel, ws[OFF_WPSI1 + mrow * 64 + j], h1);
  sh1[wv][j] = fmaxf(h1, 0.f);

  // phi L1, lanes 0..31
  if (j < 32) {
    float g1 = ws[OFF_BPHI1 + j];
    #pragma unroll
    for (int i = 0; i < 9; ++i) g1 = fmaf(x[i], ws[OFF_WPHI1 + i * 32 + j], g1);
    g1 = fmaf(sel, ws[OFF_WPHI1 + mrow * 32 + j], g1);
    sg1[wv][j] = fmaxf(g1, 0.f);
  }
  __syncthreads();

  // psi L2: h1 via LDS broadcast, weight row coalesced
  float h2 = ws[OFF_BPSI2 + j];
  #pragma unroll 8
  for (int i = 0; i < 64; ++i) h2 = fmaf(sh1[wv][i], ws[OFF_WPSI2 + i * 64 + j], h2);
  const float q = fmaxf(h2, 0.f) * mval;

  // z[h] = sum_j q_j * A2[j][h] — butterfly reduce over the wave
  const float* a2 = ws + OFF_A + (31 + j) * 4;
  float z0 = q * a2[0], z1 = q * a2[1], z2 = q * a2[2], z3 = q * a2[3];
  #pragma unroll
  for (int off = 32; off; off >>= 1) {
    z0 += __shfl_xor(z0, off, 64);
    z1 += __shfl_xor(z1, off, 64);
    z2 += __shfl_xor(z2, off, 64);
    z3 += __shfl_xor(z3, off, 64);
  }
  if (j == 0) {
    float* zo = ws + OFF_Z + (size_t)t * 4;
    zo[0] = z0; zo[1] = z1; zo[2] = z2; zo[3] = z3;
  }

  // phi L2 on lanes 0..31; pre_x on lanes 32..35 (overlapped halves)
  if (j < 32) {
    float g2 = ws[OFF_BPHI2 + j];
    #pragma unroll 8
    for (int i = 0; i < 32; ++i) g2 = fmaf(sg1[wv][i], ws[OFF_WPHI2 + i * 32 + j], g2);
    ws[OFF_PHI + (size_t)t * 32 + j] = fmaxf(g2, 0.f) * mval;
  } else if (j < 36) {
    const int h = j - 32;
    float pr = ws[OFF_A + 380 + h];
    #pragma unroll
    for (int i = 0; i < 9; ++i) pr = fmaf(x[i], ws[OFF_A + i * 4 + h], pr);
    pr = fmaf(sel, ws[OFF_A + mrow * 4 + h], pr);
    ws[OFF_PREX + (size_t)t * 4 + h] = pr;
  }
}

// ---------- K2': block-parallel scan of (cnt, z[4]) -> pre ----------
__global__ __launch_bounds__(256) void k2_scanz(float* __restrict__ ws) {
  const int b   = blockIdx.x;
  const int tid = threadIdx.x;
  __shared__ float sc[256], s0[256], s1[256], s2[256], s3[256];

  const float* mB = ws + OFF_MASK + b * P_;
  const float* zB = ws + OFF_Z    + (size_t)b * P_ * 4;
  const int p0 = tid * 4;

  float lc[4], l0[4], l1[4], l2[4], l3[4];
  float c = 0.f, z0 = 0.f, z1 = 0.f, z2 = 0.f, z3 = 0.f;
  #pragma unroll
  for (int i = 0; i < 4; ++i) {
    c  += mB[p0 + i];
    z0 += zB[(p0 + i) * 4 + 0]; z1 += zB[(p0 + i) * 4 + 1];
    z2 += zB[(p0 + i) * 4 + 2]; z3 += zB[(p0 + i) * 4 + 3];
    lc[i] = c; l0[i] = z0; l1[i] = z1; l2[i] = z2; l3[i] = z3;
  }

  float rc = c, r0 = z0, r1 = z1, r2 = z2, r3 = z3;
  sc[tid] = rc; s0[tid] = r0; s1[tid] = r1; s2[tid] = r2; s3[tid] = r3;
  __syncthreads();
  for (int off = 1; off < 256; off <<= 1) {
    float ac = 0.f, a0 = 0.f, a1 = 0.f, a2 = 0.f, a3 = 0.f;
    if (tid >= off) {
      ac = sc[tid - off]; a0 = s0[tid - off]; a1 = s1[tid - off];
      a2 = s2[tid - off]; a3 = s3[tid - off];
    }
    __syncthreads();
    rc += ac; r0 += a0; r1 += a1; r2 += a2; r3 += a3;
    sc[tid] = rc; s0[tid] = r0; s1[tid] = r1; s2[tid] = r2; s3[tid] = r3;
    __syncthreads();
  }
  const float ec = rc - c, e0 = r0 - z0, e1 = r1 - z1, e2 = r2 - z2, e3 = r3 - z3;

  const float* px  = ws + OFF_PREX + (size_t)b * P_ * 4;
  float*       pre = ws + OFF_PRE  + (size_t)b * P_ * 4;
  #pragma unroll
  for (int i = 0; i < 4; ++i) {
    const float inv = 1.f / (ec + lc[i]);
    const int p = p0 + i;
    pre[p * 4 + 0] = px[p * 4 + 0] + (e0 + l0[i]) * inv;
    pre[p * 4 + 1] = px[p * 4 + 1] + (e1 + l1[i]) * inv;
    pre[p * 4 + 2] = px[p * 4 + 2] + (e2 + l2[i]) * inv;
    pre[p * 4 + 3] = px[p * 4 + 3] + (e3 + l3[i]) * inv;
  }
}

// ---------- K4a: per-chunk softmax-state reduction ----------
__global__ __launch_bounds__(128) void k4a_chunk(float* __restrict__ ws) {
  const int ch = blockIdx.x, b = blockIdx.y;
  const int h = threadIdx.x >> 5, d = threadIdx.x & 31;
  const float* preB = ws + OFF_PRE + (size_t)b * P_ * 4;
  const float* phiB = ws + OFF_PHI + (size_t)b * P_ * 32;

  float M = -__builtin_inff(), E = 0.f, S = 0.f;
  const int pbeg = ch * CL_;
  for (int p = pbeg; p < pbeg + CL_; ++p) {
    const float v  = preB[p * 4 + h];
    const float ph = phiB[p * 32 + d];
    const float nM = fmaxf(M, v);
    const float al = __expf(M - nM);
    const float w  = __expf(v - nM);
    E = fmaf(E, al, w);
    S = fmaf(S, al, w * ph);
    M = nM;
  }
  const int base = (b * CH_ + ch) * 4 + h;
  if (d == 0) { ws[OFF_CME + base * 2] = M; ws[OFF_CME + base * 2 + 1] = E; }
  ws[OFF_CS + base * 32 + d] = S;
}

// ---------- K4b: exclusive scan of chunk states ----------
__global__ __launch_bounds__(128) void k4b_prefix(float* __restrict__ ws) {
  const int b = blockIdx.x;
  const int h = threadIdx.x >> 5, d = threadIdx.x & 31;
  float M = -__builtin_inff(), E = 0.f, S = 0.f;
  for (int ch = 0; ch < CH_; ++ch) {
    const int base = (b * CH_ + ch) * 4 + h;
    if (d == 0) { ws[OFF_PME + base * 2] = M; ws[OFF_PME + base * 2 + 1] = E; }
    ws[OFF_PS + base * 32 + d] = S;
    const float cM = ws[OFF_CME + base * 2];
    const float cE = ws[OFF_CME + base * 2 + 1];
    const float cS = ws[OFF_CS  + base * 32 + d];
    const float nM = fmaxf(M, cM);
    const float a1 = __expf(M - nM);
    const float a2 = __expf(cM - nM);
    E = E * a1 + cE * a2;
    S = S * a1 + cS * a2;
    M = nM;
  }
}

// ---------- K4c: replay chunk from prefix, write agg ----------
__global__ __launch_bounds__(128) void k4c_replay(float* __restrict__ ws) {
  const int ch = blockIdx.x, b = blockIdx.y;
  const int h = threadIdx.x >> 5, d = threadIdx.x & 31;
  const float* preB = ws + OFF_PRE + (size_t)b * P_ * 4;
  const float* phiB = ws + OFF_PHI + (size_t)b * P_ * 32;
  const float* mB   = ws + OFF_MASK + b * P_;
  float*       aggB = ws + OFF_AGG + (size_t)b * P_ * 128;

  const int base = (b * CH_ + ch) * 4 + h;
  float M = ws[OFF_PME + base * 2];
  float E = ws[OFF_PME + base * 2 + 1];
  float S = ws[OFF_PS  + base * 32 + d];

  const int pbeg = ch * CL_;
  for (int p = pbeg; p < pbeg + CL_; ++p) {
    const float v  = preB[p * 4 + h];
    const float ph = phiB[p * 32 + d];
    const float nM = fmaxf(M, v);
    const float al = __expf(M - nM);
    const float w  = __expf(v - nM);
    E = fmaf(E, al, w);
    S = fmaf(S, al, w * ph);
    M = nM;
    aggB[p * 128 + h * 32 + d] = (S / E) * mB[p];
  }
}

// ---------- K5: rho MLP, 16 tokens/block, 4 tokens/wave, lane=channel ----------
__global__ __launch_bounds__(256) void k5_rho(const float* __restrict__ ws,
                                              const void* __restrict__ mask_raw,
                                              void* __restrict__ out) {
  __shared__ float sW1[128 * 64];   // 32 KB
  __shared__ float sH1[16][64];     // 4 KB
  const int tid = threadIdx.x;
  for (int i = tid; i < 128 * 64; i += 256) sW1[i] = ws[OFF_WRHO1 + i];

  const int wv = __builtin_amdgcn_readfirstlane(tid >> 6);
  const int j  = tid & 63;
  const int t0 = blockIdx.x * 16 + wv * 4;   // this wave's 4 tokens
  const float* aggB = ws + OFF_AGG;

  const float b1 = ws[OFF_BRHO1 + j];
  float a0 = b1, a1 = b1, a2 = b1, a3 = b1;
  __syncthreads();

  #pragma unroll 8
  for (int i = 0; i < 128; ++i) {
    const float w = sW1[i * 64 + j];                       // lane-stride-1: conflict-free
    a0 = fmaf(aggB[(size_t)(t0 + 0) * 128 + i], w, a0);    // wave-uniform -> s_load
    a1 = fmaf(aggB[(size_t)(t0 + 1) * 128 + i], w, a1);
    a2 = fmaf(aggB[(size_t)(t0 + 2) * 128 + i], w, a2);
    a3 = fmaf(aggB[(size_t)(t0 + 3) * 128 + i], w, a3);
  }
  sH1[wv * 4 + 0][j] = fmaxf(a0, 0.f);
  sH1[wv * 4 + 1][j] = fmaxf(a1, 0.f);
  sH1[wv * 4 + 2][j] = fmaxf(a2, 0.f);
  sH1[wv * 4 + 3][j] = fmaxf(a3, 0.f);
  __syncthreads();

  const float b2 = ws[OFF_BRHO2 + j];
  float o0 = b2, o1 = b2, o2 = b2, o3 = b2;
  #pragma unroll 8
  for (int i = 0; i < 64; ++i) {
    const float w = ws[OFF_WRHO2 + i * 64 + j];            // L1-hot, coalesced
    o0 = fmaf(sH1[wv * 4 + 0][i], w, o0);                  // LDS broadcast
    o1 = fmaf(sH1[wv * 4 + 1][i], w, o1);
    o2 = fmaf(sH1[wv * 4 + 2][i], w, o2);
    o3 = fmaf(sH1[wv * 4 + 3][i], w, o3);
  }

  const bool isf32 = detect_f32(mask_raw);
  float r[4] = {o0, o1, o2, o3};
  #pragma unroll
  for (int k = 0; k < 4; ++k) {
    const int t = t0 + k;
    const float v = fmaxf(r[k], 0.f) * ws[OFF_MASK + t];
    if (isf32) {
      ((float*)out)[(size_t)t * 64 + j] = v;
    } else {
      __hip_bfloat16 bb = __float2bfloat16(v);
      ((__hip_bfloat16*)out)[(size_t)t * 64 + j] = bb;
    }
  }
}

extern "C" void kernel_launch(void* const* d_in, const int* in_sizes, int n_in,
                              void* d_out, int out_size, void* d_ws, size_t ws_size,
                              hipStream_t stream) {
  const int* meas = (const int*)d_in[2];
  const void* mask = d_in[3];
  float* ws = (float*)d_ws;

  s0_stage<<<96, 256, 0, stream>>>(ws, d_in[0], d_in[1], mask,
                                   d_in[4], d_in[5], d_in[6], d_in[7],
                                   d_in[8], d_in[9], d_in[10],
                                   d_in[11], d_in[12], d_in[13], d_in[14],
                                   d_in[15], d_in[16], d_in[17], d_in[18]);
  s1_fold<<<2, 256, 0, stream>>>(ws);
  k1_token<<<T_/4, 256, 0, stream>>>(ws, meas);
  k2_scanz<<<B_, 256, 0, stream>>>(ws);
  k4a_chunk<<<dim3(CH_, B_), 128, 0, stream>>>(ws);
  k4b_prefix<<<B_, 128, 0, stream>>>(ws);
  k4c_replay<<<dim3(CH_, B_), 128, 0, stream>>>(ws);
  k5_rho<<<T_/16, 256, 0, stream>>>(ws, mask, d_out);
}

// Round 6
// 162.512 us; speedup vs baseline: 4.8630x; 1.0512x over previous
//
#include <hip/hip_runtime.h>
#include <hip/hip_bf16.h>

#define B_ 16
#define P_ 1024
#define T_ (B_*P_)
#define CH_ 32          // chunks per batch for the softmax scan
#define CL_ (P_/CH_)    // 32 positions per chunk

// ---- ws layout (floats). Weights staged to f32; token inputs read raw. ----
constexpr int OFF_A     = 16;                       // 95*4 + 4 = 384
constexpr int OFF_WPSI1 = 400;                      // 1984
constexpr int OFF_BPSI1 = OFF_WPSI1 + 1984;         // 64
constexpr int OFF_WPSI2 = OFF_BPSI1 + 64;           // 4096
constexpr int OFF_BPSI2 = OFF_WPSI2 + 4096;         // 64
constexpr int OFF_WKEY  = OFF_BPSI2 + 64;           // 12160 (unused by compute; staged for completeness)
constexpr int OFF_BKEY  = OFF_WKEY  + 12160;        // 128
constexpr int OFF_QRY   = OFF_BKEY  + 128;          // 128
constexpr int OFF_WPHI1 = OFF_QRY   + 128;          // 992
constexpr int OFF_BPHI1 = OFF_WPHI1 + 992;          // 32
constexpr int OFF_WPHI2 = OFF_BPHI1 + 32;           // 1024
constexpr int OFF_BPHI2 = OFF_WPHI2 + 1024;         // 32
constexpr int OFF_WRHO1 = OFF_BPHI2 + 32;           // 8192
constexpr int OFF_BRHO1 = OFF_WRHO1 + 8192;         // 64
constexpr int OFF_WRHO2 = OFF_BRHO1 + 64;           // 4096
constexpr int OFF_BRHO2 = OFF_WRHO2 + 4096;         // 64
constexpr int OFF_PHI   = OFF_BRHO2 + 64;           // T*32
constexpr int OFF_Z     = OFF_PHI   + T_*32;        // T*4
constexpr int OFF_PREX  = OFF_Z     + T_*4;         // T*4
constexpr int OFF_PRE   = OFF_PREX  + T_*4;         // T*4
constexpr int OFF_AGG   = OFF_PRE   + T_*4;         // T*128
constexpr int OFF_CME   = OFF_AGG   + T_*128;       // B*CH*4*2 = 4096
constexpr int OFF_CS    = OFF_CME   + 4096;         // B*CH*4*32 = 65536
// end ~= 11.7 MiB

static __device__ __forceinline__ bool detect_f32(const void* mask_raw) {
  return ((*(const unsigned*)mask_raw) & 0xFFFFu) == 0u;
}
static __device__ __forceinline__ float ld_any(const void* src, int i, bool isf32) {
  if (isf32) return ((const float*)src)[i];
  return __bfloat162float(((const __hip_bfloat16*)src)[i]);
}

// ---------- S01: stage weights to f32 (blocks >=2) + fold A (blocks 0..1) ----------
__global__ __launch_bounds__(256) void s01_prep(
    float* __restrict__ ws, const void* mask,
    const void* Wpsi1, const void* bpsi1, const void* Wpsi2, const void* bpsi2,
    const void* Wkey,  const void* bkey,  const void* query,
    const void* Wphi1, const void* bphi1, const void* Wphi2, const void* bphi2,
    const void* Wrho1, const void* brho1, const void* Wrho2, const void* brho2) {
  const bool isf32 = detect_f32(mask);
  if (blockIdx.x < 2) {
    // fold: A = (W_key . query)/sqrt(dp), c0 = (b_key . query)/sqrt(dp)
    const int gid = blockIdx.x * 256 + threadIdx.x;
    if (gid >= 384) return;
    const float inv_s = 0.17677669529663687f;
    const int h = gid & 3;
    const int j = gid >> 2;  // 0..95; 95 = bias row
    float s = 0.f;
    if (j < 95) {
      for (int d = 0; d < 32; ++d)
        s += ld_any(Wkey, j * 128 + h * 32 + d, isf32) * ld_any(query, h * 32 + d, isf32);
    } else {
      for (int d = 0; d < 32; ++d)
        s += ld_any(bkey, h * 32 + d, isf32) * ld_any(query, h * 32 + d, isf32);
    }
    ws[OFF_A + gid] = s * inv_s;  // A[j][h] at j*4+h; c0[h] at 380+h
    return;
  }
  const int g  = (blockIdx.x - 2) * 256 + threadIdx.x;
  const int gs = (gridDim.x - 2) * 256;
  auto st = [&](int off, const void* src, int n) {
    for (int i = g; i < n; i += gs) ws[off + i] = ld_any(src, i, isf32);
  };
  st(OFF_WPSI1, Wpsi1, 1984); st(OFF_BPSI1, bpsi1, 64);
  st(OFF_WPSI2, Wpsi2, 4096); st(OFF_BPSI2, bpsi2, 64);
  st(OFF_WPHI1, Wphi1, 992);  st(OFF_BPHI1, bphi1, 32);
  st(OFF_WPHI2, Wphi2, 1024); st(OFF_BPHI2, bphi2, 32);
  st(OFF_WRHO1, Wrho1, 8192); st(OFF_BRHO1, brho1, 64);
  st(OFF_WRHO2, Wrho2, 4096); st(OFF_BRHO2, brho2, 64);
}

// ---------- K1: wave-per-token MLPs. 4 tokens/block, lane=channel ----------
__global__ __launch_bounds__(256) void k1_token(float* __restrict__ ws,
                                                const int* __restrict__ measp,
                                                const void* __restrict__ times,
                                                const void* __restrict__ values,
                                                const void* __restrict__ mask) {
  __shared__ float sh1[4][64];
  __shared__ float sg1[4][32];
  const bool isf32 = detect_f32(mask);
  const int tid = threadIdx.x;
  const int wv  = __builtin_amdgcn_readfirstlane(tid >> 6);
  const int j   = tid & 63;
  const int t   = blockIdx.x * 4 + wv;

  const float tval = ld_any(times, t, isf32);
  const float vval = ld_any(values, t, isf32);
  const float mval = ld_any(mask, t, isf32);
  const int   meas = measp[t];
  const float sel  = (meas > 0) ? 1.f : 0.f;
  const int   mrow = (meas > 0) ? (8 + meas) : 0;

  float x[9];
  const float posv[4] = {1.f, 10.f, 100.f, 1000.f};
  #pragma unroll
  for (int k = 0; k < 4; ++k) {
    float s, c;
    __sincosf(tval / posv[k], &s, &c);
    x[2*k] = s; x[2*k+1] = c;
  }
  x[8] = vval;

  // psi L1, channel j
  float h1 = ws[OFF_BPSI1 + j];
  #pragma unroll
  for (int i = 0; i < 9; ++i) h1 = fmaf(x[i], ws[OFF_WPSI1 + i * 64 + j], h1);
  h1 = fmaf(sel, ws[OFF_WPSI1 + mrow * 64 + j], h1);
  sh1[wv][j] = fmaxf(h1, 0.f);

  // phi L1, lanes 0..31
  if (j < 32) {
    float g1 = ws[OFF_BPHI1 + j];
    #pragma unroll
    for (int i = 0; i < 9; ++i) g1 = fmaf(x[i], ws[OFF_WPHI1 + i * 32 + j], g1);
    g1 = fmaf(sel, ws[OFF_WPHI1 + mrow * 32 + j], g1);
    sg1[wv][j] = fmaxf(g1, 0.f);
  }
  __syncthreads();

  // psi L2
  float h2 = ws[OFF_BPSI2 + j];
  #pragma unroll 8
  for (int i = 0; i < 64; ++i) h2 = fmaf(sh1[wv][i], ws[OFF_WPSI2 + i * 64 + j], h2);
  const float q = fmaxf(h2, 0.f) * mval;

  // z[h] = sum_j q_j * A2[j][h] — butterfly over the wave
  const float* a2 = ws + OFF_A + (31 + j) * 4;
  float z0 = q * a2[0], z1 = q * a2[1], z2 = q * a2[2], z3 = q * a2[3];
  #pragma unroll
  for (int off = 32; off; off >>= 1) {
    z0 += __shfl_xor(z0, off, 64);
    z1 += __shfl_xor(z1, off, 64);
    z2 += __shfl_xor(z2, off, 64);
    z3 += __shfl_xor(z3, off, 64);
  }
  if (j == 0) {
    float* zo = ws + OFF_Z + (size_t)t * 4;
    zo[0] = z0; zo[1] = z1; zo[2] = z2; zo[3] = z3;
  }

  // phi L2 on lanes 0..31; pre_x on lanes 32..35
  if (j < 32) {
    float g2 = ws[OFF_BPHI2 + j];
    #pragma unroll 8
    for (int i = 0; i < 32; ++i) g2 = fmaf(sg1[wv][i], ws[OFF_WPHI2 + i * 32 + j], g2);
    ws[OFF_PHI + (size_t)t * 32 + j] = fmaxf(g2, 0.f) * mval;
  } else if (j < 36) {
    const int h = j - 32;
    float pr = ws[OFF_A + 380 + h];
    #pragma unroll
    for (int i = 0; i < 9; ++i) pr = fmaf(x[i], ws[OFF_A + i * 4 + h], pr);
    pr = fmaf(sel, ws[OFF_A + mrow * 4 + h], pr);
    ws[OFF_PREX + (size_t)t * 4 + h] = pr;
  }
}

// ---------- K2: block-parallel scan of (cnt, z[4]) -> pre; 1 block/batch ----------
__global__ __launch_bounds__(256) void k2_scanz(float* __restrict__ ws,
                                                const void* __restrict__ mask) {
  const int b   = blockIdx.x;
  const int tid = threadIdx.x;
  const bool isf32 = detect_f32(mask);
  __shared__ float sc[256], s0[256], s1[256], s2[256], s3[256];

  const float* zB = ws + OFF_Z + (size_t)b * P_ * 4;
  const int p0 = tid * 4;

  float lc[4], l0[4], l1[4], l2[4], l3[4];
  float c = 0.f, z0 = 0.f, z1 = 0.f, z2 = 0.f, z3 = 0.f;
  #pragma unroll
  for (int i = 0; i < 4; ++i) {
    c  += ld_any(mask, b * P_ + p0 + i, isf32);
    z0 += zB[(p0 + i) * 4 + 0]; z1 += zB[(p0 + i) * 4 + 1];
    z2 += zB[(p0 + i) * 4 + 2]; z3 += zB[(p0 + i) * 4 + 3];
    lc[i] = c; l0[i] = z0; l1[i] = z1; l2[i] = z2; l3[i] = z3;
  }

  float rc = c, r0 = z0, r1 = z1, r2 = z2, r3 = z3;
  sc[tid] = rc; s0[tid] = r0; s1[tid] = r1; s2[tid] = r2; s3[tid] = r3;
  __syncthreads();
  for (int off = 1; off < 256; off <<= 1) {
    float ac = 0.f, a0 = 0.f, a1 = 0.f, a2 = 0.f, a3 = 0.f;
    if (tid >= off) {
      ac = sc[tid - off]; a0 = s0[tid - off]; a1 = s1[tid - off];
      a2 = s2[tid - off]; a3 = s3[tid - off];
    }
    __syncthreads();
    rc += ac; r0 += a0; r1 += a1; r2 += a2; r3 += a3;
    sc[tid] = rc; s0[tid] = r0; s1[tid] = r1; s2[tid] = r2; s3[tid] = r3;
    __syncthreads();
  }
  const float ec = rc - c, e0 = r0 - z0, e1 = r1 - z1, e2 = r2 - z2, e3 = r3 - z3;

  const float* px  = ws + OFF_PREX + (size_t)b * P_ * 4;
  float*       pre = ws + OFF_PRE  + (size_t)b * P_ * 4;
  #pragma unroll
  for (int i = 0; i < 4; ++i) {
    const float inv = 1.f / (ec + lc[i]);
    const int p = p0 + i;
    pre[p * 4 + 0] = px[p * 4 + 0] + (e0 + l0[i]) * inv;
    pre[p * 4 + 1] = px[p * 4 + 1] + (e1 + l1[i]) * inv;
    pre[p * 4 + 2] = px[p * 4 + 2] + (e2 + l2[i]) * inv;
    pre[p * 4 + 3] = px[p * 4 + 3] + (e3 + l3[i]) * inv;
  }
}

// ---------- K4a: per-chunk softmax-state reduction (CL=32) ----------
__global__ __launch_bounds__(128) void k4a_chunk(float* __restrict__ ws) {
  const int ch = blockIdx.x, b = blockIdx.y;
  const int h = threadIdx.x >> 5, d = threadIdx.x & 31;
  const float* preB = ws + OFF_PRE + (size_t)b * P_ * 4;
  const float* phiB = ws + OFF_PHI + (size_t)b * P_ * 32;

  float M = -__builtin_inff(), E = 0.f, S = 0.f;
  const int pbeg = ch * CL_;
  for (int p = pbeg; p < pbeg + CL_; ++p) {
    const float v  = preB[p * 4 + h];
    const float ph = phiB[p * 32 + d];
    const float nM = fmaxf(M, v);
    const float al = __expf(M - nM);
    const float w  = __expf(v - nM);
    E = fmaf(E, al, w);
    S = fmaf(S, al, w * ph);
    M = nM;
  }
  const int base = (b * CH_ + ch) * 4 + h;
  if (d == 0) { ws[OFF_CME + base * 2] = M; ws[OFF_CME + base * 2 + 1] = E; }
  ws[OFF_CS + base * 32 + d] = S;
}

// ---------- K4c: in-block prefix combine + replay chunk, write agg ----------
__global__ __launch_bounds__(128) void k4c_replay(float* __restrict__ ws,
                                                  const void* __restrict__ mask) {
  const int ch = blockIdx.x, b = blockIdx.y;
  const int h = threadIdx.x >> 5, d = threadIdx.x & 31;
  const bool isf32 = detect_f32(mask);
  const float* preB = ws + OFF_PRE + (size_t)b * P_ * 4;
  const float* phiB = ws + OFF_PHI + (size_t)b * P_ * 32;
  float*       aggB = ws + OFF_AGG + (size_t)b * P_ * 128;

  // exclusive prefix over chunk states [0, ch)
  float M = -__builtin_inff(), E = 0.f, S = 0.f;
  for (int c2 = 0; c2 < ch; ++c2) {
    const int base2 = (b * CH_ + c2) * 4 + h;
    const float cM = ws[OFF_CME + base2 * 2];
    const float cE = ws[OFF_CME + base2 * 2 + 1];
    const float cS = ws[OFF_CS  + base2 * 32 + d];
    const float nM = fmaxf(M, cM);
    const float a1 = __expf(M - nM);
    const float a2 = __expf(cM - nM);
    E = E * a1 + cE * a2;
    S = S * a1 + cS * a2;
    M = nM;
  }

  const int pbeg = ch * CL_;
  for (int p = pbeg; p < pbeg + CL_; ++p) {
    const float v  = preB[p * 4 + h];
    const float ph = phiB[p * 32 + d];
    const float nM = fmaxf(M, v);
    const float al = __expf(M - nM);
    const float w  = __expf(v - nM);
    E = fmaf(E, al, w);
    S = fmaf(S, al, w * ph);
    M = nM;
    aggB[p * 128 + h * 32 + d] = (S / E) * ld_any(mask, b * P_ + p, isf32);
  }
}

// ---------- K5: rho MLP, 16 tokens/block, 4 tokens/wave, lane=channel ----------
__global__ __launch_bounds__(256) void k5_rho(const float* __restrict__ ws,
                                              const void* __restrict__ mask_raw,
                                              void* __restrict__ out) {
  __shared__ float sW1[128 * 64];   // 32 KB
  __shared__ float sH1[16][64];     // 4 KB
  const int tid = threadIdx.x;
  for (int i = tid; i < 128 * 64; i += 256) sW1[i] = ws[OFF_WRHO1 + i];

  const int wv = __builtin_amdgcn_readfirstlane(tid >> 6);
  const int j  = tid & 63;
  const int t0 = blockIdx.x * 16 + wv * 4;
  const float* aggB = ws + OFF_AGG;

  const float b1 = ws[OFF_BRHO1 + j];
  float a0 = b1, a1 = b1, a2 = b1, a3 = b1;
  __syncthreads();

  #pragma unroll 8
  for (int i = 0; i < 128; ++i) {
    const float w = sW1[i * 64 + j];
    a0 = fmaf(aggB[(size_t)(t0 + 0) * 128 + i], w, a0);
    a1 = fmaf(aggB[(size_t)(t0 + 1) * 128 + i], w, a1);
    a2 = fmaf(aggB[(size_t)(t0 + 2) * 128 + i], w, a2);
    a3 = fmaf(aggB[(size_t)(t0 + 3) * 128 + i], w, a3);
  }
  sH1[wv * 4 + 0][j] = fmaxf(a0, 0.f);
  sH1[wv * 4 + 1][j] = fmaxf(a1, 0.f);
  sH1[wv * 4 + 2][j] = fmaxf(a2, 0.f);
  sH1[wv * 4 + 3][j] = fmaxf(a3, 0.f);
  __syncthreads();

  const float b2 = ws[OFF_BRHO2 + j];
  float o0 = b2, o1 = b2, o2 = b2, o3 = b2;
  #pragma unroll 8
  for (int i = 0; i < 64; ++i) {
    const float w = ws[OFF_WRHO2 + i * 64 + j];
    o0 = fmaf(sH1[wv * 4 + 0][i], w, o0);
    o1 = fmaf(sH1[wv * 4 + 1][i], w, o1);
    o2 = fmaf(sH1[wv * 4 + 2][i], w, o2);
    o3 = fmaf(sH1[wv * 4 + 3][i], w, o3);
  }

  const bool isf32 = detect_f32(mask_raw);
  float r[4] = {o0, o1, o2, o3};
  #pragma unroll
  for (int k = 0; k < 4; ++k) {
    const int t = t0 + k;
    const float v = fmaxf(r[k], 0.f) * ld_any(mask_raw, t, isf32);
    if (isf32) {
      ((float*)out)[(size_t)t * 64 + j] = v;
    } else {
      __hip_bfloat16 bb = __float2bfloat16(v);
      ((__hip_bfloat16*)out)[(size_t)t * 64 + j] = bb;
    }
  }
}

extern "C" void kernel_launch(void* const* d_in, const int* in_sizes, int n_in,
                              void* d_out, int out_size, void* d_ws, size_t ws_size,
                              hipStream_t stream) {
  const int* meas = (const int*)d_in[2];
  const void* times = d_in[0];
  const void* values = d_in[1];
  const void* mask = d_in[3];
  float* ws = (float*)d_ws;

  s01_prep<<<34, 256, 0, stream>>>(ws, mask,
                                   d_in[4], d_in[5], d_in[6], d_in[7],
                                   d_in[8], d_in[9], d_in[10],
                                   d_in[11], d_in[12], d_in[13], d_in[14],
                                   d_in[15], d_in[16], d_in[17], d_in[18]);
  k1_token<<<T_/4, 256, 0, stream>>>(ws, meas, times, values, mask);
  k2_scanz<<<B_, 256, 0, stream>>>(ws, mask);
  k4a_chunk<<<dim3(CH_, B_), 128, 0, stream>>>(ws);
  k4c_replay<<<dim3(CH_, B_), 128, 0, stream>>>(ws, mask);
  k5_rho<<<T_/16, 256, 0, stream>>>(ws, mask, d_out);
}